// Round 14
// baseline (65.745 us; speedup 1.0000x reference)
//
#include <hip/hip_runtime.h>

// ROI-Align (bilinear, half-pixel) — B=1, H=W=128, C=512, POOL=7, N ROIs.
// Output layout: (N, 1, 7, 7, C) flat = ((roi*49 + py*7 + px) * C + c).
//
// Round-14: one block per ROI — per-ROI corner reuse + sequential writes.
//   - A ROI's 49 bins touch only ~8-14 distinct rows x cols (corners reuse
//     ~3x within the block, L1/L2-served after first touch).
//   - Block writes the ROI's whole 98 KB output span contiguously; ROI
//     swizzle (xcd = blockIdx%8 owns rois [xcd*128,(xcd+1)*128)) gives 8
//     sequential fill-like write streams. NT stores: no L2 write-allocate.
//   - Persistent 13-iteration loop + 1-deep register prefetch keeps >=4-8
//     loads in flight per thread (fixes R12's one-shot latency bound).
//   - 1024 blocks x 512 thr = 4 blocks/CU x 8 waves = full 32 waves/CU.
// Block: 512 threads = 4 bins x 128 lanes (f32x4 over all 512 channels).

#define POOLN 7
#define FM_W 128
#define FM_C 512
#define NXCD 8

typedef float f32x4 __attribute__((ext_vector_type(4)));

__global__ __launch_bounds__(512) void roi_align_kernel(
    const float* __restrict__ fm,
    const int* __restrict__ rois,
    float* __restrict__ out,
    int nroi)
{
    // XCD-contiguous ROI swizzle (bijective when nroi % 8 == 0)
    int roi;
    if ((nroi & (NXCD - 1)) == 0) {
        const int per = nroi >> 3;
        roi = (blockIdx.x & (NXCD - 1)) * per + (blockIdx.x >> 3);
    } else {
        roi = blockIdx.x;
    }

    const int sub  = threadIdx.x >> 7;          // 0..3 — bin slot (wave-uniform)
    const int lane = threadIdx.x & 127;         // f32x4 channel index
    const int coff = lane * 4;

    const int4 r = reinterpret_cast<const int4*>(rois)[roi];
    const int x1 = r.x, y1 = r.y, x2 = r.z, y2 = r.w;
    const float sizx = (float)(x2 - x1);
    const float sizy = (float)(y2 - y1);

    // Corner offsets + weights for local bin bl (0..48).
    auto coords = [&](int bl, int& oa, int& ob, int& od, int& oe,
                      float& wxo, float& wyo) {
        const int py = bl / 7;
        const int px = bl - py * 7;

        float cy = ((float)py + 0.5f) * (sizy / (float)POOLN) - 0.5f;
        cy = fminf(fmaxf(cy, 0.0f), sizy - 1.0f);
        const float ys = cy + (float)y1;
        const int   y0 = (int)floorf(ys);
        const int   yb = min(y0 + 1, y2 - 1);
        wyo = ys - (float)y0;

        float cx = ((float)px + 0.5f) * (sizx / (float)POOLN) - 0.5f;
        cx = fminf(fmaxf(cx, 0.0f), sizx - 1.0f);
        const float xs = cx + (float)x1;
        const int   x0 = (int)floorf(xs);
        const int   xb = min(x0 + 1, x2 - 1);
        wxo = xs - (float)x0;

        oa = (y0 * FM_W + x0) * FM_C + coff;
        ob = (y0 * FM_W + xb) * FM_C + coff;
        od = (yb * FM_W + x0) * FM_C + coff;
        oe = (yb * FM_W + xb) * FM_C + coff;
    };

    int bl = sub;                                // first bin: 0..3 (< 49 always)
    int oa, ob, od, oe;
    float wx, wy;
    coords(bl, oa, ob, od, oe, wx, wy);
    f32x4 a  = *reinterpret_cast<const f32x4*>(fm + oa);
    f32x4 bb = *reinterpret_cast<const f32x4*>(fm + ob);
    f32x4 d  = *reinterpret_cast<const f32x4*>(fm + od);
    f32x4 e  = *reinterpret_cast<const f32x4*>(fm + oe);

    const size_t obase = (size_t)roi * 49 * FM_C + coff;

    for (;;) {
        const int  nbl = bl + 4;
        const bool nv  = nbl < 49;               // wave-uniform

        f32x4 na, nb, nd, ne;
        float nwx = 0.f, nwy = 0.f;
        if (nv) {
            int qa, qb, qd, qe;
            coords(nbl, qa, qb, qd, qe, nwx, nwy);
            na = *reinterpret_cast<const f32x4*>(fm + qa);
            nb = *reinterpret_cast<const f32x4*>(fm + qb);
            nd = *reinterpret_cast<const f32x4*>(fm + qd);
            ne = *reinterpret_cast<const f32x4*>(fm + qe);
        }

        // Consume current bin (loads issued one iteration ago).
        const f32x4 top = a + (bb - a) * wx;
        const f32x4 bot = d + (e - d) * wx;
        const f32x4 res = top + (bot - top) * wy;
        f32x4* o = reinterpret_cast<f32x4*>(out + obase + (size_t)bl * FM_C);
        __builtin_nontemporal_store(res, o);

        if (!nv) break;
        bl = nbl; wx = nwx; wy = nwy;
        a = na; bb = nb; d = nd; e = ne;
    }
}

extern "C" void kernel_launch(void* const* d_in, const int* in_sizes, int n_in,
                              void* d_out, int out_size, void* d_ws, size_t ws_size,
                              hipStream_t stream) {
    const float* fm   = (const float*)d_in[0];
    const int*   rois = (const int*)d_in[1];
    float*       out  = (float*)d_out;

    const int N = in_sizes[1] / 4;               // 1024 ROIs
    roi_align_kernel<<<N, 512, 0, stream>>>(fm, rois, out, N);
}

// Round 15
// 31.027 us; speedup vs baseline: 2.1190x; 2.1190x over previous
//
#include <hip/hip_runtime.h>

// ROI-Align (bilinear, half-pixel) — B=1, H=W=128, C=512, POOL=7, N ROIs.
// Output layout: (N, 1, 7, 7, C) flat = ((roi*49 + py*7 + px) * C + c).
//
// FINAL (= round-4 kernel, the empirical optimum at 30.7 µs across 7
// structurally distinct attempts):
//   - 8-way channel partition: chunk = blockIdx.x & 7 → XCD (round-robin
//     dispatch), so each XCD reads only its own 128x128x64 fp32 sub-map
//     (4 MiB = its L2). Replay-regime FETCH ≈ 18 MB (95% L2 hit on 411 MB
//     of logical reads) — proven necessary by R12/R14 (no partition →
//     FETCH 160 MB, ~2x slower).
//   - Non-temporal stores: no L2 write-allocate pollution (R11 A/B:
//     cached stores cost +4.4 µs). Write piece size 128 vs 256 B measured
//     insensitive (R8 vs R4).
//   - Epoch-split working-set halving, persistent-grid prefetch, banded
//     and per-ROI restructures all measured neutral-to-negative
//     (R8/R10/R13/R14). Mixed scattered-read + scattered-NT-write fabric
//     throughput is invariant at ~3.9-4.1 TB/s on this part; 100 MB
//     writes + 18 MB fabric reads → ~31 µs is the empirical ceiling.
// Block = 256 threads = 16 bins x 16 lanes; lane = one float4 of the chunk.

#define POOLN 7
#define FM_H 128
#define FM_W 128
#define FM_C 512
#define NXCD 8
#define CHUNK_C (FM_C / NXCD)        // 64 channels per chunk
#define BINS_PER_BLOCK 16

typedef float f32x4 __attribute__((ext_vector_type(4)));

__global__ __launch_bounds__(256) void roi_align_kernel(
    const float* __restrict__ fm,
    const int* __restrict__ rois,
    float* __restrict__ out,
    int n_bins)
{
    const int chunk  = blockIdx.x & (NXCD - 1);   // → XCD id (heuristic)
    const int group  = blockIdx.x >> 3;
    const int lane_c = threadIdx.x & 15;          // float4 index within chunk
    const int bin    = group * BINS_PER_BLOCK + (threadIdx.x >> 4);
    if (bin >= n_bins) return;

    const int roi = bin / 49;
    const int rem = bin - roi * 49;
    const int py  = rem / 7;
    const int px  = rem - py * 7;

    const int4 r = reinterpret_cast<const int4*>(rois)[roi];
    const int x1 = r.x, y1 = r.y, x2 = r.z, y2 = r.w;

    // y coordinate (half-pixel, clipped to [0, size-1], then + start)
    const float sizy = (float)(y2 - y1);
    float cy = ((float)py + 0.5f) * (sizy / (float)POOLN) - 0.5f;
    cy = fminf(fmaxf(cy, 0.0f), sizy - 1.0f);
    const float ys = cy + (float)y1;
    const int   y0 = (int)floorf(ys);
    const int   yb = min(y0 + 1, y2 - 1);
    const float wy = ys - (float)y0;

    // x coordinate
    const float sizx = (float)(x2 - x1);
    float cx = ((float)px + 0.5f) * (sizx / (float)POOLN) - 0.5f;
    cx = fminf(fmaxf(cx, 0.0f), sizx - 1.0f);
    const float xs = cx + (float)x1;
    const int   x0 = (int)floorf(xs);
    const int   xb = min(x0 + 1, x2 - 1);
    const float wx = xs - (float)x0;

    const int coff = chunk * CHUNK_C + lane_c * 4;

    const f32x4 a = *reinterpret_cast<const f32x4*>(fm + (size_t)(y0 * FM_W + x0) * FM_C + coff);
    const f32x4 b = *reinterpret_cast<const f32x4*>(fm + (size_t)(y0 * FM_W + xb) * FM_C + coff);
    const f32x4 d = *reinterpret_cast<const f32x4*>(fm + (size_t)(yb * FM_W + x0) * FM_C + coff);
    const f32x4 e = *reinterpret_cast<const f32x4*>(fm + (size_t)(yb * FM_W + xb) * FM_C + coff);

    const f32x4 top = a + (b - a) * wx;
    const f32x4 bot = d + (e - d) * wx;
    const f32x4 res = top + (bot - top) * wy;

    f32x4* o = reinterpret_cast<f32x4*>(out + (size_t)bin * FM_C + coff);
    __builtin_nontemporal_store(res, o);
}

extern "C" void kernel_launch(void* const* d_in, const int* in_sizes, int n_in,
                              void* d_out, int out_size, void* d_ws, size_t ws_size,
                              hipStream_t stream) {
    const float* fm   = (const float*)d_in[0];
    const int*   rois = (const int*)d_in[1];
    float*       out  = (float*)d_out;

    const int N      = in_sizes[1] / 4;           // 1024 ROIs
    const int n_bins = N * POOLN * POOLN;         // 50176
    const int groups = (n_bins + BINS_PER_BLOCK - 1) / BINS_PER_BLOCK;  // 3136
    dim3 grid(groups * NXCD);                     // 25088 blocks
    roi_align_kernel<<<grid, 256, 0, stream>>>(fm, rois, out, n_bins);
}